// Round 6
// baseline (100.336 us; speedup 1.0000x reference)
//
#include <hip/hip_runtime.h>

// RBF: out[b,l] = exp(-(1/256) * max(||x_b||^2 + ||l_l||^2 - 2 x_b·l_l, 0))
// B=8192, L=2048, D=256. bf16 MFMA GEMM + fused epilogue.
// R2: XOR-swizzled LDS (kept). R3: swapped MFMA -> f32x4 NT stores (kept).
// R5: 256x256 tile, 8 waves (2Mx4N), BK=64, 128 KB LDS, grid=256 (1 blk/CU),
//     bijective XCD swizzle (kept).
// R6: TRUE 8-PHASE schedule (m201/T3+T4+T5): 4 phases per K-tile, each
//     {ds_read quadrant frags || stage one 16KB half-tile (2 gld_lds)} ->
//     counted vmcnt -> barrier -> setprio(1) + 16 MFMA + setprio(0) ->
//     barrier. Stage order A0,B0,B1,A1; waits derived so each phase's
//     ds_reads are own-wave-vmcnt'd THEN barrier-published.

typedef __bf16 bf16x8 __attribute__((ext_vector_type(8)));
typedef float  f32x4  __attribute__((ext_vector_type(4)));

#define B_ROWS 8192
#define L_ROWS 2048
#define K_DIM  256

#define GLD_LDS(g, l) __builtin_amdgcn_global_load_lds(                      \
    (const __attribute__((address_space(1))) void*)(g),                      \
    (__attribute__((address_space(3))) void*)(l), 16, 0, 0)

__device__ __forceinline__ unsigned short f32_to_bf16_rne(float f) {
    union { float f; unsigned int u; } v; v.f = f;
    unsigned int u = v.u;
    unsigned int r = (u + 0x7fffu + ((u >> 16) & 1u)) >> 16;
    return (unsigned short)r;
}

// One wave per 256-float row: convert to bf16 (RNE) + fp32 squared-norm.
__global__ __launch_bounds__(256) void cvt_rows_kernel(
    const float* __restrict__ x, const float* __restrict__ lm,
    unsigned short* __restrict__ xb, unsigned short* __restrict__ lb,
    float* __restrict__ x2, float* __restrict__ l2)
{
    const int lane = threadIdx.x & 63;
    const int gw   = blockIdx.x * 4 + (threadIdx.x >> 6);
    const float* in; unsigned short* outb; float* sq; int row;
    if (gw < B_ROWS) { in = x;  outb = xb; sq = x2; row = gw; }
    else             { in = lm; outb = lb; sq = l2; row = gw - B_ROWS; }
    const float4 v = ((const float4*)(in + (size_t)row * K_DIM))[lane];
    ushort4 o;
    o.x = f32_to_bf16_rne(v.x);
    o.y = f32_to_bf16_rne(v.y);
    o.z = f32_to_bf16_rne(v.z);
    o.w = f32_to_bf16_rne(v.w);
    ((ushort4*)(outb + (size_t)row * K_DIM))[lane] = o;
    float s = v.x*v.x + v.y*v.y + v.z*v.z + v.w*v.w;
    #pragma unroll
    for (int off = 32; off > 0; off >>= 1) s += __shfl_down(s, off, 64);
    if (lane == 0) sq[row] = s;
}

// 256x256 tile, NT layout. 8 waves 2(M)x4(N); wave tile 128x64 = 8x4 frags.
// BK=64 dbuf (128 KB LDS). Per K-tile: 4 phases, quadrant order
// (mh,nh) = (0,0),(0,1),(1,0),(1,1); 16 MFMA each.
// Stage halves (16 KB each): A-h = rows with bit6==h {0-63,128-191 | 64-127,
// 192-255}; B-h = rows with bit5==h. Staged one K-tile ahead in order
// A0,B0,B1,A1 at phases p0..p3 (matches consumption distance).
__global__ __launch_bounds__(512, 2) void rbf_gemm_kernel(
    const unsigned short* __restrict__ A,   // bf16 bits [8192][256]
    const unsigned short* __restrict__ Bm,  // bf16 bits [2048][256]
    const float* __restrict__ x2,
    const float* __restrict__ l2,
    float* __restrict__ out)                // [8192][2048]
{
    __shared__ unsigned short As[2][256 * 64];  // 2 x 32 KB
    __shared__ unsigned short Bs[2][256 * 64];  // 2 x 32 KB -> 128 KB

    const int tid  = threadIdx.x;
    const int wave = tid >> 6;
    const int lane = tid & 63;
    const int wm = wave >> 2;          // 0..1 (M)
    const int wn = wave & 3;           // 0..3 (N)

    // Bijective XCD swizzle (256 blocks): XCD x gets wg [x*32, x*32+32),
    // all same bn -> B panel L2-resident per XCD.
    const int bid = blockIdx.x;
    const int wg  = (bid & 7) * 32 + (bid >> 3);
    const int bm  = wg & 31;
    const int bn  = wg >> 5;

    f32x4 acc[8][4];   // acc[mh*4+mt][nh*2+nt]
    #pragma unroll
    for (int i = 0; i < 8; ++i)
        #pragma unroll
        for (int j = 0; j < 4; ++j)
            acc[i][j] = (f32x4){0.f, 0.f, 0.f, 0.f};

    // gld_lds: lane l -> LDS base + 16*l == row l>>3 (8-aligned groups),
    // granule l&7. Swizzle LDS[row][g] = global[row][g ^ (row&7)] realized
    // via pre-swizzled global source (dest linear, rule #21).
    const int ldrow = lane >> 3;
    const int ldcol = (((lane & 7) ^ ldrow) * 8);

    const unsigned short* Ab = A  + (size_t)(bm * 256) * K_DIM;
    const unsigned short* Bb = Bm + (size_t)(bn * 256) * K_DIM;

    // One stage call = 2 gld_lds = 16 KB half-tile (128 rows x 128 B).
#define STAGE_A(buf, k0, h)                                                   \
    _Pragma("unroll")                                                         \
    for (int i = 0; i < 2; ++i) {                                             \
        const int r = i * 128 + (h) * 64 + wave * 8;                          \
        GLD_LDS(Ab + (r + ldrow) * K_DIM + (k0) + ldcol, &As[buf][r * 64]);   \
    }
#define STAGE_B(buf, k0, h)                                                   \
    _Pragma("unroll")                                                         \
    for (int i = 0; i < 2; ++i) {                                             \
        const int r = i * 128 + (wave >> 2) * 64 + (h) * 32 + (wave & 3) * 8; \
        GLD_LDS(Bb + (r + ldrow) * K_DIM + (k0) + ldcol, &Bs[buf][r * 64]);   \
    }

    // Prologue: stage tile 0 (A0,B0,B1,A1), publish A0+B0.
    STAGE_A(0, 0, 0);
    STAGE_B(0, 0, 0);
    STAGE_B(0, 0, 1);
    STAGE_A(0, 0, 1);
    asm volatile("s_waitcnt vmcnt(4)" ::: "memory");   // A0,B0 complete
    asm volatile("s_barrier" ::: "memory");

    const int xr = (lane & 7) << 4;                     // read-side XOR key
    const int osw0 = ((0  + (lane >> 4) * 16) ^ xr) >> 1;   // kk=0  (elems)
    const int osw1 = ((64 + (lane >> 4) * 16) ^ xr) >> 1;   // kk=32 (elems)

    bf16x8 af[4][2], bf0[2][2], bf1[2][2];

#define RD_A(mh)                                                              \
    _Pragma("unroll")                                                         \
    for (int mt = 0; mt < 4; ++mt) {                                          \
        const int rr = (wm * 128 + ((mh) * 4 + mt) * 16 + (lane & 15)) * 64;  \
        af[mt][0] = *(const bf16x8*)&As[cur][rr + osw0];                      \
        af[mt][1] = *(const bf16x8*)&As[cur][rr + osw1];                      \
    }
#define RD_B(dst, nh)                                                         \
    _Pragma("unroll")                                                         \
    for (int nt = 0; nt < 2; ++nt) {                                          \
        const int rr = (wn * 64 + ((nh) * 2 + nt) * 16 + (lane & 15)) * 64;   \
        dst[nt][0] = *(const bf16x8*)&Bs[cur][rr + osw0];                     \
        dst[nt][1] = *(const bf16x8*)&Bs[cur][rr + osw1];                     \
    }
#define QUAD(mh, nh, bfx)                                                     \
    __builtin_amdgcn_s_setprio(1);                                            \
    _Pragma("unroll")                                                         \
    for (int mt = 0; mt < 4; ++mt)                                            \
        _Pragma("unroll")                                                     \
        for (int nt = 0; nt < 2; ++nt)                                        \
            _Pragma("unroll")                                                 \
            for (int kk = 0; kk < 2; ++kk)                                    \
                acc[(mh)*4+mt][(nh)*2+nt] =                                   \
                    __builtin_amdgcn_mfma_f32_16x16x32_bf16(                  \
                        bfx[nt][kk], af[mt][kk], acc[(mh)*4+mt][(nh)*2+nt],   \
                        0, 0, 0);                                             \
    __builtin_amdgcn_s_setprio(0);
#define BAR asm volatile("s_barrier" ::: "memory")

    #pragma unroll
    for (int t = 0; t < 4; ++t) {      // K_DIM/64 = 4 K-tiles
        const int cur = t & 1, nxt = cur ^ 1;
        const int k0n = (t + 1) * 64;

        // ---- p0: quadrant (0,0); stage t+1 A-h0 ----
        RD_A(0); RD_B(bf0, 0);
        if (t < 3) { STAGE_A(nxt, k0n, 0);
                     asm volatile("s_waitcnt vmcnt(4)" ::: "memory"); }
        else       { asm volatile("s_waitcnt vmcnt(2)" ::: "memory"); }
        BAR;
        QUAD(0, 0, bf0);
        BAR;

        // ---- p1: quadrant (0,1); stage t+1 B-h0 ----
        RD_B(bf1, 1);
        if (t < 3) { STAGE_B(nxt, k0n, 0);
                     asm volatile("s_waitcnt vmcnt(4)" ::: "memory"); }
        else       { asm volatile("s_waitcnt vmcnt(0)" ::: "memory"); }
        BAR;
        QUAD(0, 1, bf1);
        BAR;

        // ---- p2: quadrant (1,0); stage t+1 B-h1 (no wait needed) ----
        RD_A(1);
        if (t < 3) { STAGE_B(nxt, k0n, 1); }
        BAR;
        QUAD(1, 0, bf0);
        BAR;

        // ---- p3: quadrant (1,1); stage t+1 A-h1 ----
        if (t < 3) { STAGE_A(nxt, k0n, 1);
                     asm volatile("s_waitcnt vmcnt(4)" ::: "memory"); }
        BAR;
        QUAD(1, 1, bf1);
        if (t < 3) BAR;
    }
#undef STAGE_A
#undef STAGE_B
#undef RD_A
#undef RD_B
#undef QUAD
#undef BAR

    // Epilogue (transposed D): row = ...+(lane&15), cols consecutive -> x4.
    const float gamma = 1.0f / 256.0f;
    const int row0 = bm * 256 + wm * 128 + (lane & 15);
    const int col0 = bn * 256 + wn * 64 + (lane >> 4) * 4;

    f32x4 lv[4];
    #pragma unroll
    for (int nt = 0; nt < 4; ++nt) lv[nt] = *(const f32x4*)&l2[col0 + nt * 16];

    #pragma unroll
    for (int mt = 0; mt < 8; ++mt) {
        const int row = row0 + mt * 16;
        const float xv = x2[row];
        const size_t rb = (size_t)row * L_ROWS;
        #pragma unroll
        for (int nt = 0; nt < 4; ++nt) {
            f32x4 v;
            #pragma unroll
            for (int r = 0; r < 4; ++r) {
                float d2 = fmaxf(xv + lv[nt][r] - 2.0f * acc[mt][nt][r], 0.0f);
                v[r] = __expf(-gamma * d2);
            }
            __builtin_nontemporal_store(v, (f32x4*)&out[rb + col0 + nt * 16]);
        }
    }
}

extern "C" void kernel_launch(void* const* d_in, const int* in_sizes, int n_in,
                              void* d_out, int out_size, void* d_ws, size_t ws_size,
                              hipStream_t stream) {
    const float* x  = (const float*)d_in[0];   // [8192, 256]
    const float* lm = (const float*)d_in[1];   // [2048, 256]
    float* out = (float*)d_out;

    char* ws = (char*)d_ws;
    unsigned short* xb = (unsigned short*)ws;                               // 4 MB
    unsigned short* lb = (unsigned short*)(ws + (size_t)B_ROWS*K_DIM*2);    // 1 MB
    float* x2 = (float*)(ws + (size_t)B_ROWS*K_DIM*2 + (size_t)L_ROWS*K_DIM*2);
    float* l2 = x2 + B_ROWS;

    cvt_rows_kernel<<<(B_ROWS + L_ROWS)/4, 256, 0, stream>>>(x, lm, xb, lb, x2, l2);
    rbf_gemm_kernel<<<256, 512, 0, stream>>>(xb, lb, x2, l2, out);
}